// Round 6
// baseline (5821.142 us; speedup 1.0000x reference)
//
#include <hip/hip_runtime.h>
#include <math.h>

// DCGRU encoder — 32 persistent blocks (one per layer×batch), point-to-point
// per-(t,b) flags (layer0->layer1), no grid barriers. Associative form:
//   G = cat@(W0-W2) + S@(cat@W1) + 2*S@(S@(cat@W2))
// All GEMMs contract features from node-major LDS (CAT); diffusion contracts
// nodes from an 8-interleaved LDS buffer (P8) with wave-private o-columns.
// R5 race fixes: per-(t,b) flags; CAT written only between __syncthreads;
// h re-staged from fp32 hf each step; P2 kept in P8 (pass reorder), no global
// scratch round-trip.

typedef __attribute__((ext_vector_type(8))) short bf16x8;
typedef __attribute__((ext_vector_type(4))) float f32x4;

namespace {
constexpr int NTHR = 1024;
constexpr int CATW = 264;   // CAT row stride (halfwords): 256+8
// workspace byte offsets
constexpr size_t OF_SBF = 4096;                 // bf16 [32][128][128]
constexpr size_t OF_WGT = OF_SBF + 1048576;     // bf16 [2][3][256 o][256 d]
constexpr size_t OF_WCT = OF_WGT + 786432;      // bf16 [2][3][128 o][256 d]
constexpr size_t OF_XH  = OF_WCT + 393216;      // bf16 [32][16][128][128]
constexpr size_t OF_HF  = OF_XH + 16777216;     // f32 [2][16][128][128]
constexpr size_t OF_UW  = OF_HF + 4194304;      // f32 [2][16][128][128]
}

__device__ __forceinline__ unsigned short f2bf(float x) {
  unsigned u = __float_as_uint(x);
  u += 0x7fff + ((u >> 16) & 1);   // RNE
  return (unsigned short)(u >> 16);
}
__device__ __forceinline__ uint2 pack4(f32x4 v) {
  return make_uint2((unsigned)f2bf(v[0]) | ((unsigned)f2bf(v[1]) << 16),
                    (unsigned)f2bf(v[2]) | ((unsigned)f2bf(v[3]) << 16));
}

// C[node n][o] += cat[n][d] * W[d][o]; W table pre-transposed [o][d].
__device__ __forceinline__ void gemm_pass(const unsigned short* CATb,
                                          const unsigned short* Wp,  // + o*256
                                          int l16, int quad, f32x4* acc) {
  for (int ks = 0; ks < 8; ks++) {
    const bf16x8 bf = *(const bf16x8*)(Wp + ks * 32 + quad * 8);
#pragma unroll
    for (int nt = 0; nt < 8; nt++) {
      const bf16x8 af =
          *(const bf16x8*)(CATb + (nt * 16 + l16) * CATW + ks * 32 + quad * 8);
      acc[nt] = __builtin_amdgcn_mfma_f32_16x16x32_bf16(af, bf, acc[nt], 0, 0, 0);
    }
  }
}

// C[m][o] += S[m][n] * P[n][o]; P8 node-interleaved [g=n>>3][o][n&7].
__device__ __forceinline__ void sdiff(const unsigned short* St,
                                      const unsigned short* P8o,  // + o*8
                                      int l16, int quad, f32x4* acc) {
  for (int ks = 0; ks < 4; ks++) {
    const bf16x8 bf = *(const bf16x8*)(P8o + (ks * 4 + quad) * 2048);
#pragma unroll
    for (int mt = 0; mt < 8; mt++) {
      const bf16x8 af =
          *(const bf16x8*)(St + (mt * 16 + l16) * 128 + ks * 32 + quad * 8);
      acc[mt] = __builtin_amdgcn_mfma_f32_16x16x32_bf16(af, bf, acc[mt], 0, 0, 0);
    }
  }
}

// write C-layout regs (node n = nt*16+quad*4+r, col o) into P8, scaled
__device__ __forceinline__ void store_p8(unsigned short* P8, int o, int quad,
                                         const f32x4* P, float scale) {
#pragma unroll
  for (int nt = 0; nt < 8; nt++) {
    f32x4 v = P[nt] * scale;
    *(uint2*)(P8 + ((nt * 2 + (quad >> 1)) * 256 + o) * 8 + (quad & 1) * 4) =
        pack4(v);
  }
}

__global__ void __launch_bounds__(NTHR, 1) dcgru(
    const float* __restrict__ inputs, const float* __restrict__ init_h,
    const float* __restrict__ sup,
    const float* __restrict__ Wg0, const float* __restrict__ bg0,
    const float* __restrict__ Wc0, const float* __restrict__ bc0,
    const float* __restrict__ Wg1, const float* __restrict__ bg1,
    const float* __restrict__ Wc1, const float* __restrict__ bc1,
    float* __restrict__ out, char* __restrict__ wsb) {
  extern __shared__ unsigned short LDS[];
  unsigned short* CAT = LDS;                // [128][CATW] bf16 [x | h or rh]
  unsigned short* P8  = LDS + 128 * CATW;   // [16][256][8]

  unsigned* flags = (unsigned*)wsb;         // [t*16+b]: layer0 done; [512+t]: S ready
  unsigned short* SBF = (unsigned short*)(wsb + OF_SBF);
  unsigned short* WGT = (unsigned short*)(wsb + OF_WGT);
  unsigned short* WCT = (unsigned short*)(wsb + OF_WCT);
  unsigned short* XH  = (unsigned short*)(wsb + OF_XH);
  float* HF = (float*)(wsb + OF_HF);
  float* UW = (float*)(wsb + OF_UW);

  const int bid = blockIdx.x, layer = bid >> 4, b = bid & 15;
  const int tid = threadIdx.x;
  const int lane = tid & 63, wv = tid >> 6, quad = lane >> 4, l16 = lane & 15;

  float* hf = HF + (size_t)(layer * 16 + b) * 16384;   // fp32 h [n][f]
  float* uw = UW + (size_t)(layer * 16 + b) * 16384;   // fp32 u [n][o']
  const float* bgl = layer ? bg1 : bg0;
  const float* bcl = layer ? bc1 : bc0;
  const unsigned short* WgTl = WGT + (size_t)layer * 196608;
  const unsigned short* WcTl = WCT + (size_t)layer * 98304;

  // ================= PREP =================
  {
    const float* Wg = layer ? Wg1 : Wg0;   // WGT[l][j][o][d]; j0 = W0 - W2
    for (int idx = tid; idx < 196608; idx += NTHR) {
      const int j = idx >> 16, rem = idx & 65535, o = rem >> 8, d = rem & 255;
      float v;
      if (j == 0)      v = Wg[(d * 3) * 256 + o] - Wg[(d * 3 + 2) * 256 + o];
      else if (j == 1) v = Wg[(d * 3 + 1) * 256 + o];
      else             v = Wg[(d * 3 + 2) * 256 + o];
      WGT[(size_t)layer * 196608 + idx] = f2bf(v);
    }
    const float* Wc = layer ? Wc1 : Wc0;
    for (int idx = tid; idx < 98304; idx += NTHR) {
      const int j = idx >> 15, rem = idx & 32767, o = rem >> 8, d = rem & 255;
      float v;
      if (j == 0)      v = Wc[(d * 3) * 128 + o] - Wc[(d * 3 + 2) * 128 + o];
      else if (j == 1) v = Wc[(d * 3 + 1) * 128 + o];
      else             v = Wc[(d * 3 + 2) * 128 + o];
      WCT[(size_t)layer * 98304 + idx] = f2bf(v);
    }
    const int myt = b * 2 + layer;   // this block preps S_bf[myt]
    for (int idx = tid; idx < 16384; idx += NTHR)
      SBF[(size_t)myt * 16384 + idx] = f2bf(sup[(size_t)myt * 16384 + idx]);
    for (int idx = tid; idx < 16384; idx += NTHR)
      hf[idx] = init_h[(size_t)layer * 262144 + (size_t)b * 16384 + idx];
    __syncthreads();
    if (tid == 0)
      __hip_atomic_store(&flags[512 + myt], 1u, __ATOMIC_RELEASE,
                         __HIP_MEMORY_SCOPE_AGENT);
  }

  // ================= MAIN LOOP =================
  for (int t = 0; t < 32; t++) {
    if (tid == 0) {
      while (__hip_atomic_load(&flags[512 + t], __ATOMIC_ACQUIRE,
                               __HIP_MEMORY_SCOPE_AGENT) == 0)
        __builtin_amdgcn_s_sleep(2);
      if (layer)
        while (__hip_atomic_load(&flags[t * 16 + b], __ATOMIC_ACQUIRE,
                                 __HIP_MEMORY_SCOPE_AGENT) == 0)
          __builtin_amdgcn_s_sleep(2);
    }
    __syncthreads();

    // stage CAT = [x | h] (bf16). h re-staged from fp32 hf (no carry race).
    {
      const int n = tid >> 3, f0 = (tid & 7) * 16;
      if (layer == 0) {
        const float* src = inputs + (size_t)((b * 32 + t) * 128 + n) * 128 + f0;
        uint4 a, c;
        const float4 v0 = *(const float4*)(src);
        const float4 v1 = *(const float4*)(src + 4);
        const float4 v2 = *(const float4*)(src + 8);
        const float4 v3 = *(const float4*)(src + 12);
        a.x = (unsigned)f2bf(v0.x) | ((unsigned)f2bf(v0.y) << 16);
        a.y = (unsigned)f2bf(v0.z) | ((unsigned)f2bf(v0.w) << 16);
        a.z = (unsigned)f2bf(v1.x) | ((unsigned)f2bf(v1.y) << 16);
        a.w = (unsigned)f2bf(v1.z) | ((unsigned)f2bf(v1.w) << 16);
        c.x = (unsigned)f2bf(v2.x) | ((unsigned)f2bf(v2.y) << 16);
        c.y = (unsigned)f2bf(v2.z) | ((unsigned)f2bf(v2.w) << 16);
        c.z = (unsigned)f2bf(v3.x) | ((unsigned)f2bf(v3.y) << 16);
        c.w = (unsigned)f2bf(v3.z) | ((unsigned)f2bf(v3.w) << 16);
        *(uint4*)(CAT + n * CATW + f0) = a;
        *(uint4*)(CAT + n * CATW + f0 + 8) = c;
      } else {
        const unsigned short* src = XH + (size_t)((t * 16 + b) * 128 + n) * 128 + f0;
        *(uint4*)(CAT + n * CATW + f0) = *(const uint4*)(src);
        *(uint4*)(CAT + n * CATW + f0 + 8) = *(const uint4*)(src + 8);
      }
      const float* hsrc = hf + n * 128 + f0;
      uint4 a, c;
      const float4 v0 = *(const float4*)(hsrc);
      const float4 v1 = *(const float4*)(hsrc + 4);
      const float4 v2 = *(const float4*)(hsrc + 8);
      const float4 v3 = *(const float4*)(hsrc + 12);
      a.x = (unsigned)f2bf(v0.x) | ((unsigned)f2bf(v0.y) << 16);
      a.y = (unsigned)f2bf(v0.z) | ((unsigned)f2bf(v0.w) << 16);
      a.z = (unsigned)f2bf(v1.x) | ((unsigned)f2bf(v1.y) << 16);
      a.w = (unsigned)f2bf(v1.z) | ((unsigned)f2bf(v1.w) << 16);
      c.x = (unsigned)f2bf(v2.x) | ((unsigned)f2bf(v2.y) << 16);
      c.y = (unsigned)f2bf(v2.z) | ((unsigned)f2bf(v2.w) << 16);
      c.z = (unsigned)f2bf(v3.x) | ((unsigned)f2bf(v3.y) << 16);
      c.w = (unsigned)f2bf(v3.z) | ((unsigned)f2bf(v3.w) << 16);
      *(uint4*)(CAT + n * CATW + 128 + f0) = a;
      *(uint4*)(CAT + n * CATW + 128 + f0 + 8) = c;
    }
    __syncthreads();

    const unsigned short* St = SBF + (size_t)t * 16384;
    const int o = wv * 16 + l16;

    // ===== GATES =====
    f32x4 G[8];
#pragma unroll
    for (int i = 0; i < 8; i++) G[i] = (f32x4){0.f, 0.f, 0.f, 0.f};
    {
      f32x4 P[8];
      gemm_pass(CAT, WgTl + o * 256, l16, quad, G);              // j0: cat@(W0-W2)
#pragma unroll
      for (int i = 0; i < 8; i++) P[i] = (f32x4){0.f, 0.f, 0.f, 0.f};
      gemm_pass(CAT, WgTl + 131072 + o * 256, l16, quad, P);     // j2: cat@W2
      store_p8(P8, o, quad, P, 1.f);
      asm volatile("s_waitcnt lgkmcnt(0)" ::: "memory");
      f32x4 Tt[8];
#pragma unroll
      for (int i = 0; i < 8; i++) Tt[i] = (f32x4){0.f, 0.f, 0.f, 0.f};
      sdiff(St, P8 + o * 8, l16, quad, Tt);                      // T = S@P2
      store_p8(P8, o, quad, Tt, 2.f);
      asm volatile("s_waitcnt lgkmcnt(0)" ::: "memory");
      sdiff(St, P8 + o * 8, l16, quad, G);                       // G += S@(2T)
#pragma unroll
      for (int i = 0; i < 8; i++) P[i] = (f32x4){0.f, 0.f, 0.f, 0.f};
      gemm_pass(CAT, WgTl + 65536 + o * 256, l16, quad, P);      // j1: cat@W1
      store_p8(P8, o, quad, P, 1.f);
      asm volatile("s_waitcnt lgkmcnt(0)" ::: "memory");
      sdiff(St, P8 + o * 8, l16, quad, G);                       // G += S@P1
    }
    __syncthreads();   // all waves done reading CAT h-half / P8

    // gates epilogue: r -> rh into CAT h-half (own cols); u -> uw
    {
      const float bias = bgl[o];
#pragma unroll
      for (int nt = 0; nt < 8; nt++) {
#pragma unroll
        for (int r = 0; r < 4; r++) {
          const int n = nt * 16 + quad * 4 + r;
          const float g = 1.f / (1.f + __expf(-(G[nt][r] + bias)));
          if (wv < 8) CAT[n * CATW + 128 + o] = f2bf(g * hf[n * 128 + o]);
          else        uw[n * 128 + (o - 128)] = g;
        }
      }
    }
    __syncthreads();   // rh visible before cand reads

    // ===== CAND (waves 0..7; o < 128) =====
    if (wv < 8) {
      f32x4 C[8];
#pragma unroll
      for (int i = 0; i < 8; i++) C[i] = (f32x4){0.f, 0.f, 0.f, 0.f};
      {
        f32x4 P[8];
        gemm_pass(CAT, WcTl + o * 256, l16, quad, C);            // j0
#pragma unroll
        for (int i = 0; i < 8; i++) P[i] = (f32x4){0.f, 0.f, 0.f, 0.f};
        gemm_pass(CAT, WcTl + 65536 + o * 256, l16, quad, P);    // j2
        store_p8(P8, o, quad, P, 1.f);
        asm volatile("s_waitcnt lgkmcnt(0)" ::: "memory");
        f32x4 Tt[8];
#pragma unroll
        for (int i = 0; i < 8; i++) Tt[i] = (f32x4){0.f, 0.f, 0.f, 0.f};
        sdiff(St, P8 + o * 8, l16, quad, Tt);
        store_p8(P8, o, quad, Tt, 2.f);
        asm volatile("s_waitcnt lgkmcnt(0)" ::: "memory");
        sdiff(St, P8 + o * 8, l16, quad, C);
#pragma unroll
        for (int i = 0; i < 8; i++) P[i] = (f32x4){0.f, 0.f, 0.f, 0.f};
        gemm_pass(CAT, WcTl + 32768 + o * 256, l16, quad, P);    // j1
        store_p8(P8, o, quad, P, 1.f);
        asm volatile("s_waitcnt lgkmcnt(0)" ::: "memory");
        sdiff(St, P8 + o * 8, l16, quad, C);
      }
      // cand epilogue: GRU update; writes hf/XH/out only (CAT untouched)
      const float bias = bcl[o];
#pragma unroll
      for (int nt = 0; nt < 8; nt++) {
#pragma unroll
        for (int r = 0; r < 4; r++) {
          const int n = nt * 16 + quad * 4 + r;
          const float cv = tanhf(C[nt][r] + bias);
          const float uv = uw[n * 128 + o];
          const float hv = hf[n * 128 + o];
          const float hn = uv * hv + (1.f - uv) * cv;
          hf[n * 128 + o] = hn;
          if (layer == 0) {
            XH[(size_t)((t * 16 + b) * 128 + n) * 128 + o] = f2bf(hn);
          } else {
            out[(size_t)524288 + (size_t)t * 262144 +
                (size_t)(b * 128 + n) * 128 + o] = hn;
          }
          if (t == 31)
            out[(size_t)layer * 262144 + (size_t)(b * 128 + n) * 128 + o] = hn;
        }
      }
    }
    __syncthreads();
    if (layer == 0 && tid == 0)
      __hip_atomic_store(&flags[t * 16 + b], 1u, __ATOMIC_RELEASE,
                         __HIP_MEMORY_SCOPE_AGENT);
  }
}

extern "C" void kernel_launch(void* const* d_in, const int* in_sizes, int n_in,
                              void* d_out, int out_size, void* d_ws, size_t ws_size,
                              hipStream_t stream) {
  const float* inputs = (const float*)d_in[0];
  const float* init_h = (const float*)d_in[1];
  const float* sup    = (const float*)d_in[2];
  const float* Wg0 = (const float*)d_in[3];
  const float* bg0 = (const float*)d_in[4];
  const float* Wc0 = (const float*)d_in[5];
  const float* bc0 = (const float*)d_in[6];
  const float* Wg1 = (const float*)d_in[7];
  const float* bg1 = (const float*)d_in[8];
  const float* Wc1 = (const float*)d_in[9];
  const float* bc1 = (const float*)d_in[10];
  float* out = (float*)d_out;

  const int lds_bytes = 128 * CATW * 2 + 16 * 256 * 8 * 2;  // 133120
  hipFuncSetAttribute((const void*)dcgru,
                      hipFuncAttributeMaxDynamicSharedMemorySize, lds_bytes);
  hipMemsetAsync(d_ws, 0, 4096, stream);  // zero flags
  dcgru<<<32, NTHR, lds_bytes, stream>>>(inputs, init_h, sup, Wg0, bg0, Wc0,
                                         bc0, Wg1, bg1, Wc1, bc1, out,
                                         (char*)d_ws);
}

// Round 7
// 4263.140 us; speedup vs baseline: 1.3655x; 1.3655x over previous
//
#include <hip/hip_runtime.h>
#include <math.h>

// DCGRU encoder — 32 persistent blocks (one per layer×batch), 512 threads,
// point-to-point per-(t,b) flags, no grid barriers. Associative form:
//   G = cat@(W0-W2) + S@(cat@W1) + 2*S@(S@(cat@W2))
// R7: fix R6 register-spill (VGPR 64 -> 256 budget via 8 waves/CU);
// each wave owns 2 gate o-tiles + 1 cand o-tile; combined j0+j1 sweep
// shares each A-fragment across 4 MFMA; T reuses registers.

typedef __attribute__((ext_vector_type(8))) short bf16x8;
typedef __attribute__((ext_vector_type(4))) float f32x4;

namespace {
constexpr int NTHR = 512;
constexpr int CATW = 264;   // CAT row stride (halfwords): 256+8
constexpr size_t OF_SBF = 4096;                 // bf16 [32][128][128]
constexpr size_t OF_WGT = OF_SBF + 1048576;     // bf16 [2][3][256 o][256 d]
constexpr size_t OF_WCT = OF_WGT + 786432;      // bf16 [2][3][128 o][256 d]
constexpr size_t OF_XH  = OF_WCT + 393216;      // bf16 [32][16][128][128]
constexpr size_t OF_HF  = OF_XH + 16777216;     // f32 [2][16][128][128]
constexpr size_t OF_UW  = OF_HF + 4194304;      // f32 [2][16][128][128]
}

__device__ __forceinline__ unsigned short f2bf(float x) {
  unsigned u = __float_as_uint(x);
  u += 0x7fff + ((u >> 16) & 1);   // RNE
  return (unsigned short)(u >> 16);
}
__device__ __forceinline__ uint2 pack4(f32x4 v) {
  return make_uint2((unsigned)f2bf(v[0]) | ((unsigned)f2bf(v[1]) << 16),
                    (unsigned)f2bf(v[2]) | ((unsigned)f2bf(v[3]) << 16));
}
__device__ __forceinline__ void zero8(f32x4* a) {
#pragma unroll
  for (int i = 0; i < 8; i++) a[i] = (f32x4){0.f, 0.f, 0.f, 0.f};
}

// acc[nt](n, col) += cat[n][d] * W[d][col], one W stream
__device__ __forceinline__ void gemm1(const unsigned short* CATb,
                                      const unsigned short* W0,
                                      int l16, int quad, f32x4* A0) {
  for (int ks = 0; ks < 8; ks++) {
    const bf16x8 b0 = *(const bf16x8*)(W0 + ks * 32 + quad * 8);
#pragma unroll
    for (int nt = 0; nt < 8; nt++) {
      const bf16x8 af =
          *(const bf16x8*)(CATb + (nt * 16 + l16) * CATW + ks * 32 + quad * 8);
      A0[nt] = __builtin_amdgcn_mfma_f32_16x16x32_bf16(af, b0, A0[nt], 0, 0, 0);
    }
  }
}
// two W streams share each af
__device__ __forceinline__ void gemm2(const unsigned short* CATb,
                                      const unsigned short* W0,
                                      const unsigned short* W1,
                                      int l16, int quad, f32x4* A0, f32x4* A1) {
  for (int ks = 0; ks < 8; ks++) {
    const bf16x8 b0 = *(const bf16x8*)(W0 + ks * 32 + quad * 8);
    const bf16x8 b1 = *(const bf16x8*)(W1 + ks * 32 + quad * 8);
#pragma unroll
    for (int nt = 0; nt < 8; nt++) {
      const bf16x8 af =
          *(const bf16x8*)(CATb + (nt * 16 + l16) * CATW + ks * 32 + quad * 8);
      A0[nt] = __builtin_amdgcn_mfma_f32_16x16x32_bf16(af, b0, A0[nt], 0, 0, 0);
      A1[nt] = __builtin_amdgcn_mfma_f32_16x16x32_bf16(af, b1, A1[nt], 0, 0, 0);
    }
  }
}
// four W streams share each af (combined j0+j1 over two column-tiles)
__device__ __forceinline__ void gemm4(const unsigned short* CATb,
                                      const unsigned short* W0,
                                      const unsigned short* W1,
                                      const unsigned short* W2,
                                      const unsigned short* W3,
                                      int l16, int quad,
                                      f32x4* A0, f32x4* A1, f32x4* A2, f32x4* A3) {
  for (int ks = 0; ks < 8; ks++) {
    const bf16x8 b0 = *(const bf16x8*)(W0 + ks * 32 + quad * 8);
    const bf16x8 b1 = *(const bf16x8*)(W1 + ks * 32 + quad * 8);
    const bf16x8 b2 = *(const bf16x8*)(W2 + ks * 32 + quad * 8);
    const bf16x8 b3 = *(const bf16x8*)(W3 + ks * 32 + quad * 8);
#pragma unroll
    for (int nt = 0; nt < 8; nt++) {
      const bf16x8 af =
          *(const bf16x8*)(CATb + (nt * 16 + l16) * CATW + ks * 32 + quad * 8);
      A0[nt] = __builtin_amdgcn_mfma_f32_16x16x32_bf16(af, b0, A0[nt], 0, 0, 0);
      A1[nt] = __builtin_amdgcn_mfma_f32_16x16x32_bf16(af, b1, A1[nt], 0, 0, 0);
      A2[nt] = __builtin_amdgcn_mfma_f32_16x16x32_bf16(af, b2, A2[nt], 0, 0, 0);
      A3[nt] = __builtin_amdgcn_mfma_f32_16x16x32_bf16(af, b3, A3[nt], 0, 0, 0);
    }
  }
}

// acc[mt](m, col) += S[m][n] * P[n][col]; P8 node-interleaved [n>>3][o][n&7]
__device__ __forceinline__ void sdiff(const unsigned short* St,
                                      const unsigned short* P8o,  // + o*8
                                      int l16, int quad, f32x4* acc) {
  for (int ks = 0; ks < 4; ks++) {
    const bf16x8 bf = *(const bf16x8*)(P8o + (ks * 4 + quad) * 2048);
#pragma unroll
    for (int mt = 0; mt < 8; mt++) {
      const bf16x8 af =
          *(const bf16x8*)(St + (mt * 16 + l16) * 128 + ks * 32 + quad * 8);
      acc[mt] = __builtin_amdgcn_mfma_f32_16x16x32_bf16(af, bf, acc[mt], 0, 0, 0);
    }
  }
}

__device__ __forceinline__ void store_p8(unsigned short* P8, int o, int quad,
                                         const f32x4* P, float scale) {
#pragma unroll
  for (int nt = 0; nt < 8; nt++) {
    f32x4 v = P[nt] * scale;
    *(uint2*)(P8 + ((nt * 2 + (quad >> 1)) * 256 + o) * 8 + (quad & 1) * 4) =
        pack4(v);
  }
}

__global__ void __launch_bounds__(NTHR, 2) dcgru(
    const float* __restrict__ inputs, const float* __restrict__ init_h,
    const float* __restrict__ sup,
    const float* __restrict__ Wg0, const float* __restrict__ bg0,
    const float* __restrict__ Wc0, const float* __restrict__ bc0,
    const float* __restrict__ Wg1, const float* __restrict__ bg1,
    const float* __restrict__ Wc1, const float* __restrict__ bc1,
    float* __restrict__ out, char* __restrict__ wsb) {
  extern __shared__ unsigned short LDS[];
  unsigned short* CAT = LDS;                // [128][CATW] bf16 [x | h or rh]
  unsigned short* P8  = LDS + 128 * CATW;   // [16][256][8]

  unsigned* flags = (unsigned*)wsb;
  unsigned short* SBF = (unsigned short*)(wsb + OF_SBF);
  unsigned short* WGT = (unsigned short*)(wsb + OF_WGT);
  unsigned short* WCT = (unsigned short*)(wsb + OF_WCT);
  unsigned short* XH  = (unsigned short*)(wsb + OF_XH);
  float* HF = (float*)(wsb + OF_HF);
  float* UW = (float*)(wsb + OF_UW);

  const int bid = blockIdx.x, layer = bid >> 4, b = bid & 15;
  const int tid = threadIdx.x;
  const int lane = tid & 63, wv = tid >> 6, quad = lane >> 4, l16 = lane & 15;

  float* hf = HF + (size_t)(layer * 16 + b) * 16384;
  float* uw = UW + (size_t)(layer * 16 + b) * 16384;
  const float* bgl = layer ? bg1 : bg0;
  const float* bcl = layer ? bc1 : bc0;
  const unsigned short* WgTl = WGT + (size_t)layer * 196608;
  const unsigned short* WcTl = WCT + (size_t)layer * 98304;

  // ================= PREP =================
  {
    const float* Wg = layer ? Wg1 : Wg0;   // WGT[l][j][o][d]; j0 = W0 - W2
    for (int idx = tid; idx < 196608; idx += NTHR) {
      const int j = idx >> 16, rem = idx & 65535, o = rem >> 8, d = rem & 255;
      float v;
      if (j == 0)      v = Wg[(d * 3) * 256 + o] - Wg[(d * 3 + 2) * 256 + o];
      else if (j == 1) v = Wg[(d * 3 + 1) * 256 + o];
      else             v = Wg[(d * 3 + 2) * 256 + o];
      WGT[(size_t)layer * 196608 + idx] = f2bf(v);
    }
    const float* Wc = layer ? Wc1 : Wc0;
    for (int idx = tid; idx < 98304; idx += NTHR) {
      const int j = idx >> 15, rem = idx & 32767, o = rem >> 8, d = rem & 255;
      float v;
      if (j == 0)      v = Wc[(d * 3) * 128 + o] - Wc[(d * 3 + 2) * 128 + o];
      else if (j == 1) v = Wc[(d * 3 + 1) * 128 + o];
      else             v = Wc[(d * 3 + 2) * 128 + o];
      WCT[(size_t)layer * 98304 + idx] = f2bf(v);
    }
    const int myt = b * 2 + layer;
    for (int idx = tid; idx < 16384; idx += NTHR)
      SBF[(size_t)myt * 16384 + idx] = f2bf(sup[(size_t)myt * 16384 + idx]);
    for (int idx = tid; idx < 16384; idx += NTHR)
      hf[idx] = init_h[(size_t)layer * 262144 + (size_t)b * 16384 + idx];
    __syncthreads();
    if (tid == 0)
      __hip_atomic_store(&flags[512 + myt], 1u, __ATOMIC_RELEASE,
                         __HIP_MEMORY_SCOPE_AGENT);
  }

  // ================= MAIN LOOP =================
  for (int t = 0; t < 32; t++) {
    if (tid == 0) {
      while (__hip_atomic_load(&flags[512 + t], __ATOMIC_ACQUIRE,
                               __HIP_MEMORY_SCOPE_AGENT) == 0)
        __builtin_amdgcn_s_sleep(2);
      if (layer)
        while (__hip_atomic_load(&flags[t * 16 + b], __ATOMIC_ACQUIRE,
                                 __HIP_MEMORY_SCOPE_AGENT) == 0)
          __builtin_amdgcn_s_sleep(2);
    }
    __syncthreads();

    // stage CAT = [x | h] (bf16); h re-staged from fp32 hf
    for (int p = tid; p < 1024; p += NTHR) {
      const int n = p >> 3, f0 = (p & 7) * 16;
      if (layer == 0) {
        const float* src = inputs + (size_t)((b * 32 + t) * 128 + n) * 128 + f0;
        uint4 a, c;
        const float4 v0 = *(const float4*)(src);
        const float4 v1 = *(const float4*)(src + 4);
        const float4 v2 = *(const float4*)(src + 8);
        const float4 v3 = *(const float4*)(src + 12);
        a.x = (unsigned)f2bf(v0.x) | ((unsigned)f2bf(v0.y) << 16);
        a.y = (unsigned)f2bf(v0.z) | ((unsigned)f2bf(v0.w) << 16);
        a.z = (unsigned)f2bf(v1.x) | ((unsigned)f2bf(v1.y) << 16);
        a.w = (unsigned)f2bf(v1.z) | ((unsigned)f2bf(v1.w) << 16);
        c.x = (unsigned)f2bf(v2.x) | ((unsigned)f2bf(v2.y) << 16);
        c.y = (unsigned)f2bf(v2.z) | ((unsigned)f2bf(v2.w) << 16);
        c.z = (unsigned)f2bf(v3.x) | ((unsigned)f2bf(v3.y) << 16);
        c.w = (unsigned)f2bf(v3.z) | ((unsigned)f2bf(v3.w) << 16);
        *(uint4*)(CAT + n * CATW + f0) = a;
        *(uint4*)(CAT + n * CATW + f0 + 8) = c;
      } else {
        const unsigned short* src = XH + (size_t)((t * 16 + b) * 128 + n) * 128 + f0;
        *(uint4*)(CAT + n * CATW + f0) = *(const uint4*)(src);
        *(uint4*)(CAT + n * CATW + f0 + 8) = *(const uint4*)(src + 8);
      }
      const float* hsrc = hf + n * 128 + f0;
      uint4 a, c;
      const float4 v0 = *(const float4*)(hsrc);
      const float4 v1 = *(const float4*)(hsrc + 4);
      const float4 v2 = *(const float4*)(hsrc + 8);
      const float4 v3 = *(const float4*)(hsrc + 12);
      a.x = (unsigned)f2bf(v0.x) | ((unsigned)f2bf(v0.y) << 16);
      a.y = (unsigned)f2bf(v0.z) | ((unsigned)f2bf(v0.w) << 16);
      a.z = (unsigned)f2bf(v1.x) | ((unsigned)f2bf(v1.y) << 16);
      a.w = (unsigned)f2bf(v1.z) | ((unsigned)f2bf(v1.w) << 16);
      c.x = (unsigned)f2bf(v2.x) | ((unsigned)f2bf(v2.y) << 16);
      c.y = (unsigned)f2bf(v2.z) | ((unsigned)f2bf(v2.w) << 16);
      c.z = (unsigned)f2bf(v3.x) | ((unsigned)f2bf(v3.y) << 16);
      c.w = (unsigned)f2bf(v3.z) | ((unsigned)f2bf(v3.w) << 16);
      *(uint4*)(CAT + n * CATW + 128 + f0) = a;
      *(uint4*)(CAT + n * CATW + 128 + f0 + 8) = c;
    }
    __syncthreads();

    const unsigned short* St = SBF + (size_t)t * 16384;
    const int o0 = wv * 16 + l16;        // r-columns (0..127)
    const int o1 = 128 + wv * 16 + l16;  // u-columns (128..255)

    // ===== GATES =====
    f32x4 G0[8], G1[8], P0[8], P1[8], T[8];
    zero8(P0); zero8(P1);
    gemm2(CAT, WgTl + 131072 + o0 * 256, WgTl + 131072 + o1 * 256,
          l16, quad, P0, P1);                       // j2: cat@W2 (both tiles)
    // chain q0: 2*S@(S@P2)
    store_p8(P8, o0, quad, P0, 1.f);
    zero8(T); sdiff(St, P8 + o0 * 8, l16, quad, T);
    store_p8(P8, o0, quad, T, 2.f);
    zero8(G0); sdiff(St, P8 + o0 * 8, l16, quad, G0);
    // chain q1
    store_p8(P8, o1, quad, P1, 1.f);
    zero8(T); sdiff(St, P8 + o1 * 8, l16, quad, T);
    store_p8(P8, o1, quad, T, 2.f);
    zero8(G1); sdiff(St, P8 + o1 * 8, l16, quad, G1);
    // combined j0 + j1 sweep (af shared by 4 MFMA)
    zero8(P0); zero8(P1);
    gemm4(CAT, WgTl + o0 * 256, WgTl + o1 * 256,
          WgTl + 65536 + o0 * 256, WgTl + 65536 + o1 * 256,
          l16, quad, G0, G1, P0, P1);
    store_p8(P8, o0, quad, P0, 1.f);
    sdiff(St, P8 + o0 * 8, l16, quad, G0);          // G0 += S@P1
    store_p8(P8, o1, quad, P1, 1.f);
    sdiff(St, P8 + o1 * 8, l16, quad, G1);
    __syncthreads();   // all waves done reading CAT

    // gates epilogue: G0 -> rh (CAT h-half, own cols), G1 -> u
    {
      const float br = bgl[o0], bu = bgl[o1];
#pragma unroll
      for (int nt = 0; nt < 8; nt++) {
#pragma unroll
        for (int r = 0; r < 4; r++) {
          const int n = nt * 16 + quad * 4 + r;
          const float g0 = 1.f / (1.f + __expf(-(G0[nt][r] + br)));
          const float g1 = 1.f / (1.f + __expf(-(G1[nt][r] + bu)));
          CAT[n * CATW + 128 + o0] = f2bf(g0 * hf[n * 128 + o0]);
          uw[n * 128 + o1 - 128] = g1;
        }
      }
    }
    __syncthreads();   // rh visible

    // ===== CAND (all 8 waves; o = o0 < 128) =====
    {
      f32x4 C[8];
      zero8(P0);
      gemm1(CAT, WcTl + 65536 + o0 * 256, l16, quad, P0);   // j2
      store_p8(P8, o0, quad, P0, 1.f);
      zero8(T); sdiff(St, P8 + o0 * 8, l16, quad, T);
      store_p8(P8, o0, quad, T, 2.f);
      zero8(C); sdiff(St, P8 + o0 * 8, l16, quad, C);
      zero8(P0);
      gemm2(CAT, WcTl + o0 * 256, WcTl + 32768 + o0 * 256,
            l16, quad, C, P0);                               // j0 + j1
      store_p8(P8, o0, quad, P0, 1.f);
      sdiff(St, P8 + o0 * 8, l16, quad, C);
      // epilogue: GRU update
      const float bias = bcl[o0];
#pragma unroll
      for (int nt = 0; nt < 8; nt++) {
#pragma unroll
        for (int r = 0; r < 4; r++) {
          const int n = nt * 16 + quad * 4 + r;
          const float cv = tanhf(C[nt][r] + bias);
          const float uv = uw[n * 128 + o0];
          const float hv = hf[n * 128 + o0];
          const float hn = uv * hv + (1.f - uv) * cv;
          hf[n * 128 + o0] = hn;
          if (layer == 0) {
            XH[(size_t)((t * 16 + b) * 128 + n) * 128 + o0] = f2bf(hn);
          } else {
            out[(size_t)524288 + (size_t)t * 262144 +
                (size_t)(b * 128 + n) * 128 + o0] = hn;
          }
          if (t == 31)
            out[(size_t)layer * 262144 + (size_t)(b * 128 + n) * 128 + o0] = hn;
        }
      }
    }
    __syncthreads();
    if (layer == 0 && tid == 0)
      __hip_atomic_store(&flags[t * 16 + b], 1u, __ATOMIC_RELEASE,
                         __HIP_MEMORY_SCOPE_AGENT);
  }
}

extern "C" void kernel_launch(void* const* d_in, const int* in_sizes, int n_in,
                              void* d_out, int out_size, void* d_ws, size_t ws_size,
                              hipStream_t stream) {
  const float* inputs = (const float*)d_in[0];
  const float* init_h = (const float*)d_in[1];
  const float* sup    = (const float*)d_in[2];
  const float* Wg0 = (const float*)d_in[3];
  const float* bg0 = (const float*)d_in[4];
  const float* Wc0 = (const float*)d_in[5];
  const float* bc0 = (const float*)d_in[6];
  const float* Wg1 = (const float*)d_in[7];
  const float* bg1 = (const float*)d_in[8];
  const float* Wc1 = (const float*)d_in[9];
  const float* bc1 = (const float*)d_in[10];
  float* out = (float*)d_out;

  const int lds_bytes = 128 * CATW * 2 + 16 * 256 * 8 * 2;  // 133120
  hipFuncSetAttribute((const void*)dcgru,
                      hipFuncAttributeMaxDynamicSharedMemorySize, lds_bytes);
  hipMemsetAsync(d_ws, 0, 4096, stream);
  dcgru<<<32, NTHR, lds_bytes, stream>>>(inputs, init_h, sup, Wg0, bg0, Wc0,
                                         bc0, Wg1, bg1, Wc1, bc1, out,
                                         (char*)d_ws);
}